// Round 5
// baseline (51.698 us; speedup 1.0000x reference)
//
#include <hip/hip_runtime.h>
#include <cstdint>
#include <cstddef>

typedef __attribute__((ext_vector_type(8))) short short8;
typedef __attribute__((ext_vector_type(4))) unsigned short ushort4_t;
typedef __attribute__((ext_vector_type(4))) float f32x4;

#define NF 40
#define NK 780           // 40*39/2 pairs
#define BT 32            // batch rows per block
#define THREADS 1024     // 16 waves
#define KSPLIT 2         // k-halves -> grid 512 -> 2 blocks/CU (LDS exact fit)

__device__ __forceinline__ unsigned short f2bf(float f) {
    unsigned int u = __float_as_uint(f);
    u = (u + 0x7fffu + ((u >> 16) & 1u)) >> 16;
    return (unsigned short)u;
}
__device__ __forceinline__ float bf2f(unsigned short x) {
    return __uint_as_float(((unsigned int)x) << 16);
}

// wfrag[k][half][l][t] = bf16( W[k][ (l&15)+16*half ][ 8*(l>>4)+t ] )
// = A-fragment (rows e, K-dim f) for mfma_f32_16x16x32_bf16; half = e-half.
__global__ __launch_bounds__(128) void wprep_kernel(const float* __restrict__ W,
                                                    unsigned short* __restrict__ wfrag) {
    const int k = blockIdx.x, t = threadIdx.x;
    const int half = t >> 6, l = t & 63;
    const int e = (l & 15) + 16 * half;
    const int f0 = 8 * (l >> 4);
    const float* src = W + (size_t)k * 1024 + e * 32 + f0;
    const float4 x0 = *(const float4*)src;
    const float4 x1 = *(const float4*)(src + 4);
    short8 v;
    v[0] = (short)f2bf(x0.x); v[1] = (short)f2bf(x0.y);
    v[2] = (short)f2bf(x0.z); v[3] = (short)f2bf(x0.w);
    v[4] = (short)f2bf(x1.x); v[5] = (short)f2bf(x1.y);
    v[6] = (short)f2bf(x1.z); v[7] = (short)f2bf(x1.w);
    *(short8*)(wfrag + (size_t)k * 1024 + half * 512 + l * 8) = v;
}

// embT granule (field, g): g = (b + 32*fq) ^ (field&7), holds bf16 of
// emb[b0+b][field][8*fq .. 8*fq+7]. XOR spreads bank-quads on both sides.

// reload the f32 vi register cache for row-pair (bq, bq+16) at field ii
#define RELOAD_VI()                                                                     \
    {                                                                                   \
        const int i7 = ii & 7;                                                          \
        const char* ibase = embT + (ii << 11) + eoff;                                   \
        const ushort4_t ra = *(const ushort4_t*)(ibase + (((bq      + fqlo32) ^ i7) << 4)); \
        const ushort4_t rb = *(const ushort4_t*)(ibase + (((bq + 64 + fqlo32) ^ i7) << 4)); \
        const ushort4_t rc = *(const ushort4_t*)(ibase + (((bq + 16 + fqlo32) ^ i7) << 4)); \
        const ushort4_t rd = *(const ushort4_t*)(ibase + (((bq + 80 + fqlo32) ^ i7) << 4)); \
        vf00 = bf2f(ra[0]); vf01 = bf2f(ra[1]); vf02 = bf2f(ra[2]); vf03 = bf2f(ra[3]); \
        vf04 = bf2f(rb[0]); vf05 = bf2f(rb[1]); vf06 = bf2f(rb[2]); vf07 = bf2f(rb[3]); \
        vf10 = bf2f(rc[0]); vf11 = bf2f(rc[1]); vf12 = bf2f(rc[2]); vf13 = bf2f(rc[3]); \
        vf14 = bf2f(rd[0]); vf15 = bf2f(rd[1]); vf16 = bf2f(rd[2]); vf17 = bf2f(rd[3]); \
    }

// one k: tmp[e,b] = W[k]·vj  (4 MFMAs: 2 e-halves x 2 b-halves), then dot with vi
#define KSTEP(AE0, AE1, OREG)                                                           \
    {                                                                                   \
        const int j7 = jj & 7;                                                          \
        const char* jbase = embT + (jj << 11);                                          \
        const short8 vj0 = *(const short8*)(jbase + (((bq      + fq32) ^ j7) << 4));    \
        const short8 vj1 = *(const short8*)(jbase + (((bq + 16 + fq32) ^ j7) << 4));    \
        f32x4 t00 = {}, t01 = {}, t10 = {}, t11 = {};                                   \
        t00 = __builtin_amdgcn_mfma_f32_16x16x32_bf16(AE0, vj0, t00, 0, 0, 0);          \
        t10 = __builtin_amdgcn_mfma_f32_16x16x32_bf16(AE1, vj0, t10, 0, 0, 0);          \
        t01 = __builtin_amdgcn_mfma_f32_16x16x32_bf16(AE0, vj1, t01, 0, 0, 0);          \
        t11 = __builtin_amdgcn_mfma_f32_16x16x32_bf16(AE1, vj1, t11, 0, 0, 0);          \
        float p0 = t00[0]*vf00 + t00[1]*vf01 + t00[2]*vf02 + t00[3]*vf03                \
                 + t10[0]*vf04 + t10[1]*vf05 + t10[2]*vf06 + t10[3]*vf07;               \
        float p1 = t01[0]*vf10 + t01[1]*vf11 + t01[2]*vf12 + t01[3]*vf13                \
                 + t11[0]*vf14 + t11[1]*vf15 + t11[2]*vf16 + t11[3]*vf17;               \
        p0 += __shfl_xor(p0, 16); p0 += __shfl_xor(p0, 32);                             \
        p1 += __shfl_xor(p1, 16); p1 += __shfl_xor(p1, 32);                             \
        OREG = (l & 16) ? p1 : p0;                                                      \
        ++jj;                                                                           \
        if (jj == NF) { ++ii; jj = ii + 1; RELOAD_VI(); }                               \
    }

__global__ __launch_bounds__(THREADS, 2) void bil_kernel(const float* __restrict__ emb,
                                                         const unsigned short* __restrict__ wfrag,
                                                         float* __restrict__ out) {
    __shared__ __align__(16) char embT[NF * 2048];   // 81920 B; 2 blocks = exactly 160 KiB

    const int tid = threadIdx.x;
    const int btile = blockIdx.x >> 1;
    const int khalf = blockIdx.x & 1;
    const int b0 = btile * BT;

    // --- Stage 32-row tile: coalesced 32B global reads, conflict-free swizzled LDS writes ---
    for (int u = tid; u < BT * 160; u += THREADS) {  // exactly 5 iterations
        const int bb = u / 160;
        const int t = u - 160 * bb;
        const int field = t >> 2;
        const int fq = t & 3;
        const float* src = emb + (size_t)(b0 + bb) * (NF * 32) + field * 32 + 8 * fq;
        const float4 x0 = *(const float4*)src;
        const float4 x1 = *(const float4*)(src + 4);
        short8 v;
        v[0] = (short)f2bf(x0.x); v[1] = (short)f2bf(x0.y);
        v[2] = (short)f2bf(x0.z); v[3] = (short)f2bf(x0.w);
        v[4] = (short)f2bf(x1.x); v[5] = (short)f2bf(x1.y);
        v[6] = (short)f2bf(x1.z); v[7] = (short)f2bf(x1.w);
        const int g = (bb + 32 * fq) ^ (field & 7);
        *(short8*)(embT + field * 2048 + g * 16) = v;
    }
    __syncthreads();

    const int ww = (tid >> 6) + 16 * khalf;  // global wave id 0..31
    const int l = tid & 63;
    const int bq = l & 15;
    const int h = l >> 4;
    const int fq32 = h << 5;            // vj granule fq*32
    const int fqlo32 = (h >> 1) << 5;   // vi granule fq*32 (e-low block)
    const int eoff = (h & 1) * 8;       // byte offset within vi granule

    // Contiguous pp range per global wave (12..13 pp each; 390 pp total).
    const int ps = 2 * ((195 * ww) >> 5);
    const int pe = 2 * ((195 * (ww + 1)) >> 5);

    // initial (ii, jj) for k = 2*ps  (i-major triu order)
    int ii = 0, jj;
    {
        int kk = 2 * ps, len = 39;
        while (kk >= len) { kk -= len; ++ii; --len; }
        jj = ii + 1 + kk;
    }

    float vf00, vf01, vf02, vf03, vf04, vf05, vf06, vf07;
    float vf10, vf11, vf12, vf13, vf14, vf15, vf16, vf17;
    RELOAD_VI();

    const short8* wf = (const short8*)wfrag;   // idx = k*128 + half*64 + l

    // Prologue: W fragments for the first group (4 k's).
    size_t gb = (size_t)(2 * ps) * 128;
    short8 c0e0 = wf[gb + l],       c0e1 = wf[gb + 64 + l];
    short8 c1e0 = wf[gb + 128 + l], c1e1 = wf[gb + 192 + l];
    short8 c2e0 = wf[gb + 256 + l], c2e1 = wf[gb + 320 + l];
    short8 c3e0 = wf[gb + 384 + l], c3e1 = wf[gb + 448 + l];

    int pg = ps;
    for (; pg + 2 <= pe; pg += 2) {             // group = 2 pp = 4 k
        const bool more = (pg + 2) < pe;        // another group OR a 1-pp tail
        short8 n0e0 = {}, n0e1 = {}, n1e0 = {}, n1e1 = {};
        short8 n2e0 = {}, n2e1 = {}, n3e0 = {}, n3e1 = {};
        if (more) {                              // prefetch next 4 k's 8 fragments
            const size_t nb = (size_t)(2 * (pg + 2)) * 128;
            n0e0 = wf[nb + l];       n0e1 = wf[nb + 64 + l];
            n1e0 = wf[nb + 128 + l]; n1e1 = wf[nb + 192 + l];
            n2e0 = wf[nb + 256 + l]; n2e1 = wf[nb + 320 + l];
            n3e0 = wf[nb + 384 + l]; n3e1 = wf[nb + 448 + l];
        }
        float o0, o1, o2, o3;
        KSTEP(c0e0, c0e1, o0);
        KSTEP(c1e0, c1e1, o1);
        KSTEP(c2e0, c2e1, o2);
        KSTEP(c3e0, c3e1, o3);
        if (l < 32) {                            // lane l owns row b0+l; 16B aligned
            float4 st; st.x = o0; st.y = o1; st.z = o2; st.w = o3;
            *(float4*)(out + (size_t)(b0 + l) * NK + 2 * pg) = st;
        }
        if (more) {
            c0e0 = n0e0; c0e1 = n0e1; c1e0 = n1e0; c1e1 = n1e1;
            c2e0 = n2e0; c2e1 = n2e1; c3e0 = n3e0; c3e1 = n3e1;
        }
    }
    if (pg < pe) {                               // 1-pp tail (2 k), frags already resident
        float o0, o1;
        KSTEP(c0e0, c0e1, o0);
        KSTEP(c1e0, c1e1, o1);
        if (l < 32) {
            float2 st; st.x = o0; st.y = o1;
            *(float2*)(out + (size_t)(b0 + l) * NK + 2 * pg) = st;
        }
    }
}

extern "C" void kernel_launch(void* const* d_in, const int* in_sizes, int n_in,
                              void* d_out, int out_size, void* d_ws, size_t ws_size,
                              hipStream_t stream) {
    const float* emb = (const float*)d_in[0];
    const float* W   = (const float*)d_in[1];
    float* out = (float*)d_out;
    unsigned short* wfrag = (unsigned short*)d_ws;   // 780*1024*2 B = 1.6 MB scratch

    wprep_kernel<<<dim3(NK), dim3(128), 0, stream>>>(W, wfrag);
    bil_kernel<<<dim3((8192 / BT) * KSPLIT), dim3(THREADS), 0, stream>>>(emb, wfrag, out);
}

// Round 6
// 41.332 us; speedup vs baseline: 1.2508x; 1.2508x over previous
//
#include <hip/hip_runtime.h>
#include <cstdint>
#include <cstddef>

typedef __attribute__((ext_vector_type(8))) short short8;
typedef __attribute__((ext_vector_type(4))) unsigned short ushort4_t;
typedef __attribute__((ext_vector_type(16))) float f32x16;

#define NF 40
#define NK 780           // 40*39/2 pairs
#define BT 32            // batch rows per block
#define THREADS 1024     // 16 waves, grid 256 = 1 block/CU

__device__ __forceinline__ unsigned short f2bf(float f) {
    unsigned int u = __float_as_uint(f);
    u = (u + 0x7fffu + ((u >> 16) & 1u)) >> 16;
    return (unsigned short)u;
}
__device__ __forceinline__ float bf2f(unsigned short x) {
    return __uint_as_float(((unsigned int)x) << 16);
}

// wfrag[k][half][l][t] = bf16( W[k][ e = l&31 ][ 16*half + 8*(l>>5) + t ] )
// = A-fragment (rows e, K-dim f) for mfma_f32_32x32x16_bf16; half = f-half.
__global__ __launch_bounds__(128) void wprep_kernel(const float* __restrict__ W,
                                                    unsigned short* __restrict__ wfrag) {
    const int k = blockIdx.x, t = threadIdx.x;
    const int half = t >> 6, l = t & 63;
    const int e = l & 31;
    const int f0 = 16 * half + 8 * (l >> 5);
    const float* src = W + (size_t)k * 1024 + e * 32 + f0;
    const float4 x0 = *(const float4*)src;
    const float4 x1 = *(const float4*)(src + 4);
    short8 v;
    v[0] = (short)f2bf(x0.x); v[1] = (short)f2bf(x0.y);
    v[2] = (short)f2bf(x0.z); v[3] = (short)f2bf(x0.w);
    v[4] = (short)f2bf(x1.x); v[5] = (short)f2bf(x1.y);
    v[6] = (short)f2bf(x1.z); v[7] = (short)f2bf(x1.w);
    *(short8*)(wfrag + (size_t)k * 1024 + half * 512 + l * 8) = v;
}

// embT granule (field, g): g = (b + 32*fq) ^ (field&7), holds bf16 of
// emb[b0+b][field][8*fq .. 8*fq+7]. XOR spreads bank-quads on both sides.

// vi f32 cache for lane's b-col: vf[4q+s] = vi[b32][8q + 4*h32 + s]  (C rows)
#define RELOAD_VI()                                                                     \
    {                                                                                   \
        const int i7 = ii & 7;                                                          \
        const char* ibase = embT + (ii << 11) + eoff;                                   \
        const ushort4_t r0 = *(const ushort4_t*)(ibase + (((b32     ) ^ i7) << 4));     \
        const ushort4_t r1 = *(const ushort4_t*)(ibase + (((b32 + 32) ^ i7) << 4));     \
        const ushort4_t r2 = *(const ushort4_t*)(ibase + (((b32 + 64) ^ i7) << 4));     \
        const ushort4_t r3 = *(const ushort4_t*)(ibase + (((b32 + 96) ^ i7) << 4));     \
        vf0  = bf2f(r0[0]); vf1  = bf2f(r0[1]); vf2  = bf2f(r0[2]); vf3  = bf2f(r0[3]); \
        vf4  = bf2f(r1[0]); vf5  = bf2f(r1[1]); vf6  = bf2f(r1[2]); vf7  = bf2f(r1[3]); \
        vf8  = bf2f(r2[0]); vf9  = bf2f(r2[1]); vf10 = bf2f(r2[2]); vf11 = bf2f(r2[3]); \
        vf12 = bf2f(r3[0]); vf13 = bf2f(r3[1]); vf14 = bf2f(r3[2]); vf15 = bf2f(r3[3]); \
    }

// one k: t[e,b] = W[k]·vj (2 chained 32x32x16 over f-halves), dot with cached vi, reduce
#define KSTEP(A0, A1, OREG)                                                             \
    {                                                                                   \
        const int j7 = jj & 7;                                                          \
        const char* jbase = embT + (jj << 11);                                          \
        const short8 vj0 = *(const short8*)(jbase + (((b32 + fq0) ^ j7) << 4));         \
        const short8 vj1 = *(const short8*)(jbase + (((b32 + fq1) ^ j7) << 4));         \
        f32x16 t = {};                                                                  \
        t = __builtin_amdgcn_mfma_f32_32x32x16_bf16(A0, vj0, t, 0, 0, 0);               \
        t = __builtin_amdgcn_mfma_f32_32x32x16_bf16(A1, vj1, t, 0, 0, 0);               \
        float p = t[0]*vf0  + t[1]*vf1  + t[2]*vf2   + t[3]*vf3                         \
                + t[4]*vf4  + t[5]*vf5  + t[6]*vf6   + t[7]*vf7                         \
                + t[8]*vf8  + t[9]*vf9  + t[10]*vf10 + t[11]*vf11                       \
                + t[12]*vf12+ t[13]*vf13+ t[14]*vf14 + t[15]*vf15;                      \
        p += __shfl_xor(p, 32);                                                         \
        OREG = p;                                                                       \
        ++jj;                                                                           \
        if (jj == NF) { ++ii; jj = ii + 1; RELOAD_VI(); }                               \
    }

// unconditional 2-k W-fragment load (address clamped; reads are always valid)
#define LOADW2(R0, R1, R2, R3, KB)                                                      \
    {                                                                                   \
        const int kbc = (KB) > 778 ? 778 : (KB);                                        \
        const size_t bs = (size_t)kbc << 7;                                             \
        R0 = wf[bs + l];       R1 = wf[bs + 64 + l];                                    \
        R2 = wf[bs + 128 + l]; R3 = wf[bs + 192 + l];                                   \
    }

__global__ __launch_bounds__(THREADS) void bil_kernel(const float* __restrict__ emb,
                                                      const unsigned short* __restrict__ wfrag,
                                                      float* __restrict__ out) {
    __shared__ __align__(16) char embT[NF * 2048];   // 81920 B

    const int tid = threadIdx.x;
    const int b0 = blockIdx.x * BT;

    // --- Stage 32-row tile: coalesced 32B global reads, conflict-free swizzled LDS writes ---
    for (int u = tid; u < BT * 160; u += THREADS) {  // exactly 5 iterations
        const int bb = u / 160;
        const int t = u - 160 * bb;
        const int field = t >> 2;
        const int fq = t & 3;
        const float* src = emb + (size_t)(b0 + bb) * (NF * 32) + field * 32 + 8 * fq;
        const float4 x0 = *(const float4*)src;
        const float4 x1 = *(const float4*)(src + 4);
        short8 v;
        v[0] = (short)f2bf(x0.x); v[1] = (short)f2bf(x0.y);
        v[2] = (short)f2bf(x0.z); v[3] = (short)f2bf(x0.w);
        v[4] = (short)f2bf(x1.x); v[5] = (short)f2bf(x1.y);
        v[6] = (short)f2bf(x1.z); v[7] = (short)f2bf(x1.w);
        const int g = (bb + 32 * fq) ^ (field & 7);
        *(short8*)(embT + field * 2048 + g * 16) = v;
    }
    __syncthreads();

    const int ww = tid >> 6;            // wave 0..15
    const int l = tid & 63;
    const int b32 = l & 31;             // lane's batch row (C col)
    const int h32 = l >> 5;
    const int fq0 = 32 * h32;           // vj granule offset, f-half 0
    const int fq1 = 64 + 32 * h32;      // f-half 1
    const int eoff = 8 * h32;           // byte offset within vi granule

    // k-range per wave, multiple of 4 (48..52 k each)
    const int ks = 4 * ((195 * ww) >> 4);
    const int ke = 4 * ((195 * (ww + 1)) >> 4);

    // initial (ii, jj) for k = ks  (i-major triu order)
    int ii = 0, jj;
    {
        int kk = ks, len = 39;
        while (kk >= len) { kk -= len; ++ii; --len; }
        jj = ii + 1 + kk;
    }

    float vf0, vf1, vf2, vf3, vf4, vf5, vf6, vf7;
    float vf8, vf9, vf10, vf11, vf12, vf13, vf14, vf15;
    RELOAD_VI();

    const short8* wf = (const short8*)wfrag;   // idx = k*128 + half*64 + l

    short8 a0, a1, a2, a3;      // bank A: 2 k's fragments
    short8 bb0, bb1, bb2, bb3;  // bank B
    LOADW2(a0, a1, a2, a3, ks);

    int kcur = ks;
    while (kcur + 8 <= ke) {
        float o0, o1, o2, o3, o4, o5, o6, o7;
        LOADW2(bb0, bb1, bb2, bb3, kcur + 2);
        KSTEP(a0, a1, o0);  KSTEP(a2, a3, o1);
        LOADW2(a0, a1, a2, a3, kcur + 4);
        KSTEP(bb0, bb1, o2); KSTEP(bb2, bb3, o3);
        LOADW2(bb0, bb1, bb2, bb3, kcur + 6);
        KSTEP(a0, a1, o4);  KSTEP(a2, a3, o5);
        LOADW2(a0, a1, a2, a3, kcur + 8);
        KSTEP(bb0, bb1, o6); KSTEP(bb2, bb3, o7);
        if (l < 32) {                           // 32 contiguous bytes per lane
            float* orow = out + (size_t)(b0 + l) * NK + kcur;
            float4 s0; s0.x = o0; s0.y = o1; s0.z = o2; s0.w = o3;
            float4 s1; s1.x = o4; s1.y = o5; s1.z = o6; s1.w = o7;
            *(float4*)orow = s0;
            *(float4*)(orow + 4) = s1;
        }
        kcur += 8;
    }
    if (kcur < ke) {                            // 4-k tail; bank A holds kcur..kcur+1
        float o0, o1, o2, o3;
        LOADW2(bb0, bb1, bb2, bb3, kcur + 2);
        KSTEP(a0, a1, o0);  KSTEP(a2, a3, o1);
        KSTEP(bb0, bb1, o2); KSTEP(bb2, bb3, o3);
        if (l < 32) {
            float4 s0; s0.x = o0; s0.y = o1; s0.z = o2; s0.w = o3;
            *(float4*)(out + (size_t)(b0 + l) * NK + kcur) = s0;
        }
    }
}

extern "C" void kernel_launch(void* const* d_in, const int* in_sizes, int n_in,
                              void* d_out, int out_size, void* d_ws, size_t ws_size,
                              hipStream_t stream) {
    const float* emb = (const float*)d_in[0];
    const float* W   = (const float*)d_in[1];
    float* out = (float*)d_out;
    unsigned short* wfrag = (unsigned short*)d_ws;   // 780*1024*2 B = 1.6 MB scratch

    wprep_kernel<<<dim3(NK), dim3(128), 0, stream>>>(W, wfrag);
    bil_kernel<<<dim3(8192 / BT), dim3(THREADS), 0, stream>>>(emb, wfrag, out);
}